// Round 2
// baseline (219.194 us; speedup 1.0000x reference)
//
#include <hip/hip_runtime.h>
#include <hip/hip_bf16.h>
#include <math.h>

#define M_  4
#define B_  2048
#define K_  32
#define D_  256
#define DZ_ 128
#define PAD 68

// ---------------------------------------------------------------------------
// K0: Wqk[m][z][d] = sum_e W_Q[z][e] * W_K[m][d][e]   (fold W_Q into W_K)
// ---------------------------------------------------------------------------
__global__ void __launch_bounds__(256) k0_wqk(const float* __restrict__ W_Q,
                                              const float* __restrict__ W_K,
                                              float* __restrict__ Wqk) {
    int mz = blockIdx.x;
    int m = mz >> 7, z = mz & 127;
    int d = threadIdx.x;
    __shared__ float wq[D_];
    wq[d] = W_Q[z * D_ + d];
    __syncthreads();
    const float* wk = W_K + (m * D_ + d) * D_;
    float acc = 0.f;
#pragma unroll 8
    for (int e = 0; e < D_; ++e) acc = fmaf(wq[e], wk[e], acc);
    Wqk[(m * DZ_ + z) * D_ + d] = acc;
}

// ---------------------------------------------------------------------------
// K1: Qk[m][b][d] = sum_z z_anc[b][z] * Wqk[m][z][d]
// ---------------------------------------------------------------------------
__global__ void __launch_bounds__(256) k1_qk(const float* __restrict__ z_anc,
                                             const float* __restrict__ Wqk,
                                             float* __restrict__ Qk) {
    int m = blockIdx.z;
    int b0 = blockIdx.x * 64, d0 = blockIdx.y * 64;
    int t = threadIdx.x, tx = t & 15, ty = t >> 4;
    __shared__ float As[64 * PAD];
    __shared__ float Bs[64 * PAD];
    float c[4][4] = {};
    for (int kc = 0; kc < DZ_; kc += 64) {
#pragma unroll
        for (int it = 0; it < 4; ++it) {
            int s = it * 256 + t, bi = s >> 4, k4 = (s & 15) * 4;
            *(float4*)&As[bi * PAD + k4] =
                *(const float4*)&z_anc[(b0 + bi) * DZ_ + kc + k4];
        }
#pragma unroll
        for (int it = 0; it < 4; ++it) {
            int s = it * 256 + t, kk = s >> 4, d4 = (s & 15) * 4;
            *(float4*)&Bs[kk * PAD + d4] =
                *(const float4*)&Wqk[(m * DZ_ + kc + kk) * D_ + d0 + d4];
        }
        __syncthreads();
#pragma unroll 4
        for (int kk = 0; kk < 64; ++kk) {
            float a[4];
#pragma unroll
            for (int i = 0; i < 4; ++i) a[i] = As[(ty * 4 + i) * PAD + kk];
            float4 b4 = *(const float4*)&Bs[kk * PAD + tx * 4];
#pragma unroll
            for (int i = 0; i < 4; ++i) {
                c[i][0] = fmaf(a[i], b4.x, c[i][0]);
                c[i][1] = fmaf(a[i], b4.y, c[i][1]);
                c[i][2] = fmaf(a[i], b4.z, c[i][2]);
                c[i][3] = fmaf(a[i], b4.w, c[i][3]);
            }
        }
        __syncthreads();
    }
#pragma unroll
    for (int i = 0; i < 4; ++i) {
        float4 v = make_float4(c[i][0], c[i][1], c[i][2], c[i][3]);
        *(float4*)&Qk[(m * B_ + b0 + ty * 4 + i) * D_ + d0 + tx * 4] = v;
    }
}

// ---------------------------------------------------------------------------
// K2: one block per (b, m). h kept entirely in registers (8 x float4/thread).
//   scores -> softmax (wave0) -> at[k] (vw folded in)
//   hbar[b][m*D+d] = sum_k at[k]*h[k][d]   (register partials + LDS reduce)
//   out[b][d]     += sum_k at[k]*lbl_delta[b][k][m][d]   (atomicAdd)
// LDS ~4.4 KB -> occupancy VGPR-limited (~7 waves/SIMD).
// ---------------------------------------------------------------------------
__global__ void __launch_bounds__(256) k2_main(
    const float* __restrict__ h_nei, const float* __restrict__ ew_anc,
    const float* __restrict__ vmask, const float* __restrict__ lbl_delta,
    const float* __restrict__ lbl_w, const float* __restrict__ Qk,
    const float* __restrict__ log_vw,
    float* __restrict__ hbar, float* __restrict__ out)
{
    int b = blockIdx.x, m = blockIdx.y;
    int t = threadIdx.x;
    int w = t >> 6, l = t & 63;
    __shared__ float sc[K_];
    __shared__ float at[K_];
    __shared__ float part[4 * D_];   // [wave][d]

    // vw[m] = softmax(log_vw)[m] — tiny, uniform, redundant per thread
    float lv0 = log_vw[0], lv1 = log_vw[1], lv2 = log_vw[2], lv3 = log_vw[3];
    float mv = fmaxf(fmaxf(lv0, lv1), fmaxf(lv2, lv3));
    float e0 = expf(lv0 - mv), e1 = expf(lv1 - mv),
          e2 = expf(lv2 - mv), e3 = expf(lv3 - mv);
    float vw_m = ((m == 0) ? e0 : (m == 1) ? e1 : (m == 2) ? e2 : e3)
                 / (e0 + e1 + e2 + e3);

    // early independent loads for the score adjustment (lanes 0..31 of wave 0)
    float adjv = 0.f, vmv = 1.f;
    if (t < K_) {
        int idx = (b * K_ + t) * M_ + m;
        adjv = logf(ew_anc[idx] + 1e-6f) + lbl_w[idx];
        vmv = vmask[idx];
    }

    // Phase A: load h into registers, score partials, cross-lane reduce
    const float* hb = h_nei + ((size_t)(m * B_ + b)) * (K_ * D_);
    float4 q4 = *(const float4*)&Qk[(m * B_ + b) * D_ + 4 * l];
    float4 h4[8];
    float accs[8];
#pragma unroll
    for (int i = 0; i < 8; ++i) {
        int s = i * 256 + t;                 // row k = 4*i + w, cols 4l..4l+3
        h4[i] = *(const float4*)&hb[4 * s];
        accs[i] = h4[i].x * q4.x + h4[i].y * q4.y + h4[i].z * q4.z + h4[i].w * q4.w;
    }
#pragma unroll
    for (int i = 0; i < 8; ++i) {
        float v = accs[i];
        v += __shfl_xor(v, 32); v += __shfl_xor(v, 16); v += __shfl_xor(v, 8);
        v += __shfl_xor(v, 4);  v += __shfl_xor(v, 2);  v += __shfl_xor(v, 1);
        if (l == 0) sc[i * 4 + w] = v;
    }
    __syncthreads();

    // Phase B: softmax over K=32, lanes 0..31 of wave 0, shfl-parallel
    if (t < K_) {
        float s = (vmv == 0.f) ? -1e9f : sc[t] * 0.0625f + adjv;
        float mx = s;
        mx = fmaxf(mx, __shfl_xor(mx, 16)); mx = fmaxf(mx, __shfl_xor(mx, 8));
        mx = fmaxf(mx, __shfl_xor(mx, 4));  mx = fmaxf(mx, __shfl_xor(mx, 2));
        mx = fmaxf(mx, __shfl_xor(mx, 1));
        float ee = expf(s - mx);
        float ds = ee;
        ds += __shfl_xor(ds, 16); ds += __shfl_xor(ds, 8); ds += __shfl_xor(ds, 4);
        ds += __shfl_xor(ds, 2);  ds += __shfl_xor(ds, 1);
        at[t] = (ee / ds) * vw_m;            // fold vw[m] here
    }
    __syncthreads();

    // Phase C1: attn-weighted h from registers -> per-wave partial in LDS
    float4 p4 = make_float4(0.f, 0.f, 0.f, 0.f);
#pragma unroll
    for (int i = 0; i < 8; ++i) {
        float a = at[i * 4 + w];             // LDS broadcast (wave-uniform)
        p4.x = fmaf(a, h4[i].x, p4.x);
        p4.y = fmaf(a, h4[i].y, p4.y);
        p4.z = fmaf(a, h4[i].z, p4.z);
        p4.w = fmaf(a, h4[i].w, p4.w);
    }
    *(float4*)&part[w * D_ + 4 * l] = p4;

    // Phase D: lbl_delta dot (independent global loads overlap barrier below)
    const float* ldp = lbl_delta + (size_t)b * (K_ * M_ * D_) + m * D_;
    float acc = 0.f;
#pragma unroll 8
    for (int k = 0; k < K_; ++k)
        acc = fmaf(at[k], ldp[k * (M_ * D_) + t], acc);
    atomicAdd(&out[b * D_ + t], acc);
    __syncthreads();

    // Phase C2: cross-wave reduce, write hbar in [b][m*D+d] layout
    float hv = part[t] + part[D_ + t] + part[2 * D_ + t] + part[3 * D_ + t];
    hbar[(size_t)b * (M_ * D_) + m * D_ + t] = hv;
}

// ---------------------------------------------------------------------------
// K3: out[b][e] += sum_{kk} hbar[b][kk] * W_Vflat[kk][e]   (kk = m*256+d)
// split-K over 8 chunks of 128; 64x64 tiles; atomicAdd accumulation
// ---------------------------------------------------------------------------
__global__ void __launch_bounds__(256) k3_gemm(const float* __restrict__ hbar,
                                               const float* __restrict__ W_V,
                                               float* __restrict__ out) {
    int b0 = blockIdx.x * 64, e0 = blockIdx.y * 64;
    int kc0 = blockIdx.z * 128;
    int t = threadIdx.x, tx = t & 15, ty = t >> 4;
    __shared__ float As[64 * PAD];
    __shared__ float Bs[64 * PAD];
    float c[4][4] = {};
    for (int kc = kc0; kc < kc0 + 128; kc += 64) {
#pragma unroll
        for (int it = 0; it < 4; ++it) {
            int s = it * 256 + t, bi = s >> 4, k4 = (s & 15) * 4;
            *(float4*)&As[bi * PAD + k4] =
                *(const float4*)&hbar[(size_t)(b0 + bi) * (M_ * D_) + kc + k4];
        }
#pragma unroll
        for (int it = 0; it < 4; ++it) {
            int s = it * 256 + t, kk = s >> 4, e4 = (s & 15) * 4;
            *(float4*)&Bs[kk * PAD + e4] =
                *(const float4*)&W_V[(size_t)(kc + kk) * D_ + e0 + e4];
        }
        __syncthreads();
#pragma unroll 4
        for (int kk = 0; kk < 64; ++kk) {
            float a[4];
#pragma unroll
            for (int i = 0; i < 4; ++i) a[i] = As[(ty * 4 + i) * PAD + kk];
            float4 b4 = *(const float4*)&Bs[kk * PAD + tx * 4];
#pragma unroll
            for (int i = 0; i < 4; ++i) {
                c[i][0] = fmaf(a[i], b4.x, c[i][0]);
                c[i][1] = fmaf(a[i], b4.y, c[i][1]);
                c[i][2] = fmaf(a[i], b4.z, c[i][2]);
                c[i][3] = fmaf(a[i], b4.w, c[i][3]);
            }
        }
        __syncthreads();
    }
#pragma unroll
    for (int i = 0; i < 4; ++i)
#pragma unroll
        for (int j = 0; j < 4; ++j)
            atomicAdd(&out[(b0 + ty * 4 + i) * D_ + e0 + tx * 4 + j], c[i][j]);
}

// ---------------------------------------------------------------------------
extern "C" void kernel_launch(void* const* d_in, const int* in_sizes, int n_in,
                              void* d_out, int out_size, void* d_ws, size_t ws_size,
                              hipStream_t stream) {
    const float* h_nei     = (const float*)d_in[0];
    const float* ew_anc    = (const float*)d_in[1];
    const float* vmask     = (const float*)d_in[2];
    const float* z_anc     = (const float*)d_in[3];
    const float* lbl_delta = (const float*)d_in[4];
    const float* lbl_w     = (const float*)d_in[5];
    const float* W_Q       = (const float*)d_in[6];
    const float* W_K       = (const float*)d_in[7];
    const float* W_V       = (const float*)d_in[8];
    const float* log_vw    = (const float*)d_in[9];
    float* out = (float*)d_out;

    // ws layout (floats): Wqk[4*128*256] | Qk[4*2048*256] | hbar[2048*1024]
    float* ws   = (float*)d_ws;
    float* Wqk  = ws;
    float* Qk   = ws + (M_ * DZ_ * D_);
    float* hbar = ws + (M_ * DZ_ * D_) + (M_ * B_ * D_);

    hipMemsetAsync(out, 0, (size_t)B_ * D_ * sizeof(float), stream);

    k0_wqk<<<M_ * DZ_, 256, 0, stream>>>(W_Q, W_K, Wqk);

    dim3 g1(B_ / 64, D_ / 64, M_);
    k1_qk<<<g1, 256, 0, stream>>>(z_anc, Wqk, Qk);

    dim3 g2(B_, M_);
    k2_main<<<g2, 256, 0, stream>>>(h_nei, ew_anc, vmask, lbl_delta, lbl_w,
                                    Qk, log_vw, hbar, out);

    dim3 g3(B_ / 64, D_ / 64, M_ * D_ / 128);
    k3_gemm<<<g3, 256, 0, stream>>>(hbar, W_V, out);
}

// Round 3
// 180.032 us; speedup vs baseline: 1.2175x; 1.2175x over previous
//
#include <hip/hip_runtime.h>
#include <hip/hip_bf16.h>
#include <math.h>

#define M_  4
#define B_  2048
#define K_  32
#define D_  256
#define DZ_ 128
#define PAD 68

// ---------------------------------------------------------------------------
// K0: Wqk[m][z][d] = sum_e W_Q[z][e] * W_K[m][d][e]   (fold W_Q into W_K)
// ---------------------------------------------------------------------------
__global__ void __launch_bounds__(256) k0_wqk(const float* __restrict__ W_Q,
                                              const float* __restrict__ W_K,
                                              float* __restrict__ Wqk) {
    int mz = blockIdx.x;
    int m = mz >> 7, z = mz & 127;
    int d = threadIdx.x;
    __shared__ float wq[D_];
    wq[d] = W_Q[z * D_ + d];
    __syncthreads();
    const float* wk = W_K + (m * D_ + d) * D_;
    float acc = 0.f;
#pragma unroll 8
    for (int e = 0; e < D_; ++e) acc = fmaf(wq[e], wk[e], acc);
    Wqk[(m * DZ_ + z) * D_ + d] = acc;
}

// ---------------------------------------------------------------------------
// K1: Qk[m][b][d] = sum_z z_anc[b][z] * Wqk[m][z][d]
// ---------------------------------------------------------------------------
__global__ void __launch_bounds__(256) k1_qk(const float* __restrict__ z_anc,
                                             const float* __restrict__ Wqk,
                                             float* __restrict__ Qk) {
    int m = blockIdx.z;
    int b0 = blockIdx.x * 64, d0 = blockIdx.y * 64;
    int t = threadIdx.x, tx = t & 15, ty = t >> 4;
    __shared__ float As[64 * PAD];
    __shared__ float Bs[64 * PAD];
    float c[4][4] = {};
    for (int kc = 0; kc < DZ_; kc += 64) {
#pragma unroll
        for (int it = 0; it < 4; ++it) {
            int s = it * 256 + t, bi = s >> 4, k4 = (s & 15) * 4;
            *(float4*)&As[bi * PAD + k4] =
                *(const float4*)&z_anc[(b0 + bi) * DZ_ + kc + k4];
        }
#pragma unroll
        for (int it = 0; it < 4; ++it) {
            int s = it * 256 + t, kk = s >> 4, d4 = (s & 15) * 4;
            *(float4*)&Bs[kk * PAD + d4] =
                *(const float4*)&Wqk[(m * DZ_ + kc + kk) * D_ + d0 + d4];
        }
        __syncthreads();
#pragma unroll 4
        for (int kk = 0; kk < 64; ++kk) {
            float a[4];
#pragma unroll
            for (int i = 0; i < 4; ++i) a[i] = As[(ty * 4 + i) * PAD + kk];
            float4 b4 = *(const float4*)&Bs[kk * PAD + tx * 4];
#pragma unroll
            for (int i = 0; i < 4; ++i) {
                c[i][0] = fmaf(a[i], b4.x, c[i][0]);
                c[i][1] = fmaf(a[i], b4.y, c[i][1]);
                c[i][2] = fmaf(a[i], b4.z, c[i][2]);
                c[i][3] = fmaf(a[i], b4.w, c[i][3]);
            }
        }
        __syncthreads();
    }
#pragma unroll
    for (int i = 0; i < 4; ++i) {
        float4 v = make_float4(c[i][0], c[i][1], c[i][2], c[i][3]);
        *(float4*)&Qk[(m * B_ + b0 + ty * 4 + i) * D_ + d0 + tx * 4] = v;
    }
}

// ---------------------------------------------------------------------------
// K2: one block per (b,m), m FASTEST in grid order (sibling blocks share
// lbl_delta rows). ALL global loads (8 h float4 + 8 lbl float4 + Qk float4)
// issued at entry for max memory-level parallelism; 3 barriers total.
//   hbar[b][m*D+d] = vw_m * sum_k at[k]*h[k][d]          -> ws
//   lblp[m][b][d]  = vw_m * sum_k at[k]*lbl[b][k][m][d]  -> ws (no atomics)
// ---------------------------------------------------------------------------
__global__ void __launch_bounds__(256) k2_main(
    const float* __restrict__ h_nei, const float* __restrict__ ew_anc,
    const float* __restrict__ vmask, const float* __restrict__ lbl_delta,
    const float* __restrict__ lbl_w, const float* __restrict__ Qk,
    const float* __restrict__ log_vw,
    float* __restrict__ hbar, float* __restrict__ lblp)
{
    int bm = blockIdx.x;
    int b = bm >> 2, m = bm & 3;
    int t = threadIdx.x, w = t >> 6, l = t & 63;
    __shared__ float sc[K_], at[K_];
    __shared__ float partA[4 * D_], partB[4 * D_];

    // --- issue ALL global loads up front (17 dwordx4 in flight per thread) ---
    const float* hb = h_nei + ((size_t)(m * B_ + b)) * (K_ * D_);
    float4 h4[8];                       // h[k=4i+w][4l..4l+3]
#pragma unroll
    for (int i = 0; i < 8; ++i)
        h4[i] = *(const float4*)&hb[4 * (i * 256 + t)];

    const float* ldb = lbl_delta + (size_t)b * (K_ * M_ * D_) + m * D_;
    float4 ld4[8];                      // lbl[b][k=8w+i][m][4l..4l+3]
#pragma unroll
    for (int i = 0; i < 8; ++i)
        ld4[i] = *(const float4*)&ldb[(size_t)(w * 8 + i) * (M_ * D_) + 4 * l];

    float4 q4 = *(const float4*)&Qk[(m * B_ + b) * D_ + 4 * l];

    float adjv = 0.f, vmv = 1.f;
    if (t < K_) {
        int idx = (b * K_ + t) * M_ + m;
        adjv = logf(ew_anc[idx] + 1e-6f) + lbl_w[idx];
        vmv = vmask[idx];
    }

    // vw[m] = softmax(log_vw)[m] — tiny, uniform
    float lv0 = log_vw[0], lv1 = log_vw[1], lv2 = log_vw[2], lv3 = log_vw[3];
    float mv = fmaxf(fmaxf(lv0, lv1), fmaxf(lv2, lv3));
    float e0 = expf(lv0 - mv), e1 = expf(lv1 - mv),
          e2 = expf(lv2 - mv), e3 = expf(lv3 - mv);
    float vw_m = ((m == 0) ? e0 : (m == 1) ? e1 : (m == 2) ? e2 : e3)
                 / (e0 + e1 + e2 + e3);

    // --- scores: per-row dot partials + cross-lane reduce ---
#pragma unroll
    for (int i = 0; i < 8; ++i) {
        float v = h4[i].x * q4.x + h4[i].y * q4.y + h4[i].z * q4.z + h4[i].w * q4.w;
        v += __shfl_xor(v, 32); v += __shfl_xor(v, 16); v += __shfl_xor(v, 8);
        v += __shfl_xor(v, 4);  v += __shfl_xor(v, 2);  v += __shfl_xor(v, 1);
        if (l == 0) sc[i * 4 + w] = v;
    }
    __syncthreads();

    // --- softmax over K=32 in lanes 0..31 of wave 0 ---
    if (t < K_) {
        float s = (vmv == 0.f) ? -1e9f : sc[t] * 0.0625f + adjv;
        float mx = s;
        mx = fmaxf(mx, __shfl_xor(mx, 16)); mx = fmaxf(mx, __shfl_xor(mx, 8));
        mx = fmaxf(mx, __shfl_xor(mx, 4));  mx = fmaxf(mx, __shfl_xor(mx, 2));
        mx = fmaxf(mx, __shfl_xor(mx, 1));
        float ee = expf(s - mx);
        float ds = ee;
        ds += __shfl_xor(ds, 16); ds += __shfl_xor(ds, 8); ds += __shfl_xor(ds, 4);
        ds += __shfl_xor(ds, 2);  ds += __shfl_xor(ds, 1);
        at[t] = (ee / ds) * vw_m;       // fold vw[m]
    }
    __syncthreads();

    // --- both weighted sums from registers, dual LDS reduce buffers ---
    float4 pA = make_float4(0.f, 0.f, 0.f, 0.f);
    float4 pB = make_float4(0.f, 0.f, 0.f, 0.f);
#pragma unroll
    for (int i = 0; i < 8; ++i) {
        float a = at[i * 4 + w];        // h rows: k = 4i + w
        pA.x = fmaf(a, h4[i].x, pA.x);
        pA.y = fmaf(a, h4[i].y, pA.y);
        pA.z = fmaf(a, h4[i].z, pA.z);
        pA.w = fmaf(a, h4[i].w, pA.w);
        float g = at[w * 8 + i];        // lbl rows: k = 8w + i
        pB.x = fmaf(g, ld4[i].x, pB.x);
        pB.y = fmaf(g, ld4[i].y, pB.y);
        pB.z = fmaf(g, ld4[i].z, pB.z);
        pB.w = fmaf(g, ld4[i].w, pB.w);
    }
    *(float4*)&partA[w * D_ + 4 * l] = pA;
    *(float4*)&partB[w * D_ + 4 * l] = pB;
    __syncthreads();

    float hv = partA[t] + partA[D_ + t] + partA[2 * D_ + t] + partA[3 * D_ + t];
    hbar[(size_t)b * (M_ * D_) + m * D_ + t] = hv;
    float lv = partB[t] + partB[D_ + t] + partB[2 * D_ + t] + partB[3 * D_ + t];
    lblp[((size_t)m * B_ + b) * D_ + t] = lv;
}

// ---------------------------------------------------------------------------
// K3: out[b][e] = sum_kk hbar[b][kk]*W_Vflat[kk][e] + sum_m lblp[m][b][e]
// Single pass K=1024 (no split-K, no atomics, no memset). 32x64 tiles,
// grid (64,4) = 256 blocks; thread computes 2x4 outputs.
// ---------------------------------------------------------------------------
__global__ void __launch_bounds__(256) k3_gemm(const float* __restrict__ hbar,
                                               const float* __restrict__ W_V,
                                               const float* __restrict__ lblp,
                                               float* __restrict__ out) {
    int b0 = blockIdx.x * 32, e0 = blockIdx.y * 64;
    int t = threadIdx.x, tx = t & 15, ty = t >> 4;
    __shared__ float As[32 * PAD];
    __shared__ float Bs[64 * PAD];
    float c[2][4] = {};
    for (int kc = 0; kc < M_ * D_; kc += 64) {
#pragma unroll
        for (int it = 0; it < 2; ++it) {
            int s = it * 256 + t, bi = s >> 4, k4 = (s & 15) * 4;
            *(float4*)&As[bi * PAD + k4] =
                *(const float4*)&hbar[(size_t)(b0 + bi) * (M_ * D_) + kc + k4];
        }
#pragma unroll
        for (int it = 0; it < 4; ++it) {
            int s = it * 256 + t, kk = s >> 4, e4 = (s & 15) * 4;
            *(float4*)&Bs[kk * PAD + e4] =
                *(const float4*)&W_V[(size_t)(kc + kk) * D_ + e0 + e4];
        }
        __syncthreads();
#pragma unroll 4
        for (int kk = 0; kk < 64; ++kk) {
            float a0 = As[(ty * 2 + 0) * PAD + kk];
            float a1 = As[(ty * 2 + 1) * PAD + kk];
            float4 b4 = *(const float4*)&Bs[kk * PAD + tx * 4];
            c[0][0] = fmaf(a0, b4.x, c[0][0]);
            c[0][1] = fmaf(a0, b4.y, c[0][1]);
            c[0][2] = fmaf(a0, b4.z, c[0][2]);
            c[0][3] = fmaf(a0, b4.w, c[0][3]);
            c[1][0] = fmaf(a1, b4.x, c[1][0]);
            c[1][1] = fmaf(a1, b4.y, c[1][1]);
            c[1][2] = fmaf(a1, b4.z, c[1][2]);
            c[1][3] = fmaf(a1, b4.w, c[1][3]);
        }
        __syncthreads();
    }
#pragma unroll
    for (int i = 0; i < 2; ++i) {
        int row = b0 + ty * 2 + i, col = e0 + tx * 4;
        float4 s = make_float4(c[i][0], c[i][1], c[i][2], c[i][3]);
#pragma unroll
        for (int mm = 0; mm < 4; ++mm) {
            float4 lp = *(const float4*)&lblp[((size_t)mm * B_ + row) * D_ + col];
            s.x += lp.x; s.y += lp.y; s.z += lp.z; s.w += lp.w;
        }
        *(float4*)&out[(size_t)row * D_ + col] = s;
    }
}

// ---------------------------------------------------------------------------
extern "C" void kernel_launch(void* const* d_in, const int* in_sizes, int n_in,
                              void* d_out, int out_size, void* d_ws, size_t ws_size,
                              hipStream_t stream) {
    const float* h_nei     = (const float*)d_in[0];
    const float* ew_anc    = (const float*)d_in[1];
    const float* vmask     = (const float*)d_in[2];
    const float* z_anc     = (const float*)d_in[3];
    const float* lbl_delta = (const float*)d_in[4];
    const float* lbl_w     = (const float*)d_in[5];
    const float* W_Q       = (const float*)d_in[6];
    const float* W_K       = (const float*)d_in[7];
    const float* W_V       = (const float*)d_in[8];
    const float* log_vw    = (const float*)d_in[9];
    float* out = (float*)d_out;

    // ws layout (floats):
    //   Wqk[4*128*256] | Qk[4*2048*256] | hbar[2048*1024] | lblp[4*2048*256]
    float* ws   = (float*)d_ws;
    float* Wqk  = ws;
    float* Qk   = Wqk + (M_ * DZ_ * D_);
    float* hbar = Qk + (M_ * B_ * D_);
    float* lblp = hbar + (B_ * M_ * D_);

    k0_wqk<<<M_ * DZ_, 256, 0, stream>>>(W_Q, W_K, Wqk);

    dim3 g1(B_ / 64, D_ / 64, M_);
    k1_qk<<<g1, 256, 0, stream>>>(z_anc, Wqk, Qk);

    k2_main<<<B_ * M_, 256, 0, stream>>>(h_nei, ew_anc, vmask, lbl_delta,
                                         lbl_w, Qk, log_vw, hbar, lblp);

    dim3 g3(B_ / 32, D_ / 64);
    k3_gemm<<<g3, 256, 0, stream>>>(hbar, W_V, lblp, out);
}

// Round 4
// 175.138 us; speedup vs baseline: 1.2516x; 1.0279x over previous
//
#include <hip/hip_runtime.h>
#include <hip/hip_bf16.h>
#include <math.h>

#define M_  4
#define B_  2048
#define K_  32
#define D_  256
#define DZ_ 128
#define PAD 68

typedef float f32x4 __attribute__((ext_vector_type(4)));

// ---------------------------------------------------------------------------
// K0: Wqk[m][z][d] = sum_e W_Q[z][e] * W_K[m][d][e]   (fold W_Q into W_K)
// ---------------------------------------------------------------------------
__global__ void __launch_bounds__(256) k0_wqk(const float* __restrict__ W_Q,
                                              const float* __restrict__ W_K,
                                              float* __restrict__ Wqk) {
    int mz = blockIdx.x;
    int m = mz >> 7, z = mz & 127;
    int d = threadIdx.x;
    __shared__ float wq[D_];
    wq[d] = W_Q[z * D_ + d];
    __syncthreads();
    const float* wk = W_K + (m * D_ + d) * D_;
    float acc = 0.f;
#pragma unroll 8
    for (int e = 0; e < D_; ++e) acc = fmaf(wq[e], wk[e], acc);
    Wqk[(m * DZ_ + z) * D_ + d] = acc;
}

// ---------------------------------------------------------------------------
// K1: Qk[m][b][d] = sum_z z_anc[b][z] * Wqk[m][z][d]
// ---------------------------------------------------------------------------
__global__ void __launch_bounds__(256) k1_qk(const float* __restrict__ z_anc,
                                             const float* __restrict__ Wqk,
                                             float* __restrict__ Qk) {
    int m = blockIdx.z;
    int b0 = blockIdx.x * 64, d0 = blockIdx.y * 64;
    int t = threadIdx.x, tx = t & 15, ty = t >> 4;
    __shared__ float As[64 * PAD];
    __shared__ float Bs[64 * PAD];
    float c[4][4] = {};
    for (int kc = 0; kc < DZ_; kc += 64) {
#pragma unroll
        for (int it = 0; it < 4; ++it) {
            int s = it * 256 + t, bi = s >> 4, k4 = (s & 15) * 4;
            *(float4*)&As[bi * PAD + k4] =
                *(const float4*)&z_anc[(b0 + bi) * DZ_ + kc + k4];
        }
#pragma unroll
        for (int it = 0; it < 4; ++it) {
            int s = it * 256 + t, kk = s >> 4, d4 = (s & 15) * 4;
            *(float4*)&Bs[kk * PAD + d4] =
                *(const float4*)&Wqk[(m * DZ_ + kc + kk) * D_ + d0 + d4];
        }
        __syncthreads();
#pragma unroll 4
        for (int kk = 0; kk < 64; ++kk) {
            float a[4];
#pragma unroll
            for (int i = 0; i < 4; ++i) a[i] = As[(ty * 4 + i) * PAD + kk];
            float4 b4 = *(const float4*)&Bs[kk * PAD + tx * 4];
#pragma unroll
            for (int i = 0; i < 4; ++i) {
                c[i][0] = fmaf(a[i], b4.x, c[i][0]);
                c[i][1] = fmaf(a[i], b4.y, c[i][1]);
                c[i][2] = fmaf(a[i], b4.z, c[i][2]);
                c[i][3] = fmaf(a[i], b4.w, c[i][3]);
            }
        }
        __syncthreads();
    }
#pragma unroll
    for (int i = 0; i < 4; ++i) {
        float4 v = make_float4(c[i][0], c[i][1], c[i][2], c[i][3]);
        *(float4*)&Qk[(m * B_ + b0 + ty * 4 + i) * D_ + d0 + tx * 4] = v;
    }
}

// ---------------------------------------------------------------------------
// K2: one block per (b,m), m fastest. All 17 dwordx4 + 3 dword loads are
// FORCED into one issue cluster by a register-residency asm fence (the
// compiler otherwise sinks loads to minimize VGPRs -> serial latency chains;
// R3 evidence: VGPR=44 vs 68 needed, 1.87 TB/s, 20us/block for 64KB).
// ---------------------------------------------------------------------------
__global__ void __launch_bounds__(256) k2_main(
    const float* __restrict__ h_nei, const float* __restrict__ ew_anc,
    const float* __restrict__ vmask, const float* __restrict__ lbl_delta,
    const float* __restrict__ lbl_w, const float* __restrict__ Qk,
    const float* __restrict__ log_vw,
    float* __restrict__ hbar, float* __restrict__ lblp)
{
    int bm = blockIdx.x;
    int b = bm >> 2, m = bm & 3;
    int t = threadIdx.x, w = t >> 6, l = t & 63;
    __shared__ float sc[K_], at[K_];
    __shared__ float partA[4 * D_], partB[4 * D_];

    // --- issue ALL global loads up front ---
    const float* hb = h_nei + ((size_t)(m * B_ + b)) * (K_ * D_);
    f32x4 h4[8];                        // h[k=4i+w][4l..4l+3]
#pragma unroll
    for (int i = 0; i < 8; ++i)
        h4[i] = *(const f32x4*)&hb[4 * (i * 256 + t)];

    const float* ldb = lbl_delta + (size_t)b * (K_ * M_ * D_) + m * D_;
    f32x4 ld4[8];                       // lbl[b][k=8w+i][m][4l..4l+3]
#pragma unroll
    for (int i = 0; i < 8; ++i)
        ld4[i] = *(const f32x4*)&ldb[(size_t)(w * 8 + i) * (M_ * D_) + 4 * l];

    f32x4 q4 = *(const f32x4*)&Qk[(m * B_ + b) * D_ + 4 * l];

    float ew_v = 0.f, lw_v = 0.f, vm_v = 1.f;
    if (t < K_) {
        int idx = (b * K_ + t) * M_ + m;
        ew_v = ew_anc[idx];
        lw_v = lbl_w[idx];
        vm_v = vmask[idx];
    }

    // Register-residency fence: all loaded values must be materialized here.
    // Forces clustered issue of all loads + a single vmcnt wait.
    asm volatile("" ::
        "v"(h4[0]), "v"(h4[1]), "v"(h4[2]), "v"(h4[3]),
        "v"(h4[4]), "v"(h4[5]), "v"(h4[6]), "v"(h4[7]),
        "v"(ld4[0]), "v"(ld4[1]), "v"(ld4[2]), "v"(ld4[3]),
        "v"(ld4[4]), "v"(ld4[5]), "v"(ld4[6]), "v"(ld4[7]),
        "v"(q4), "v"(ew_v), "v"(lw_v), "v"(vm_v));

    // vw[m] = softmax(log_vw)[m] — tiny, uniform
    float lv0 = log_vw[0], lv1 = log_vw[1], lv2 = log_vw[2], lv3 = log_vw[3];
    float mv = fmaxf(fmaxf(lv0, lv1), fmaxf(lv2, lv3));
    float e0 = expf(lv0 - mv), e1 = expf(lv1 - mv),
          e2 = expf(lv2 - mv), e3 = expf(lv3 - mv);
    float vw_m = ((m == 0) ? e0 : (m == 1) ? e1 : (m == 2) ? e2 : e3)
                 / (e0 + e1 + e2 + e3);

    // --- scores: per-row dot partials + cross-lane reduce ---
#pragma unroll
    for (int i = 0; i < 8; ++i) {
        float v = h4[i].x * q4.x + h4[i].y * q4.y + h4[i].z * q4.z + h4[i].w * q4.w;
        v += __shfl_xor(v, 32); v += __shfl_xor(v, 16); v += __shfl_xor(v, 8);
        v += __shfl_xor(v, 4);  v += __shfl_xor(v, 2);  v += __shfl_xor(v, 1);
        if (l == 0) sc[i * 4 + w] = v;
    }
    __syncthreads();

    // --- softmax over K=32 in lanes 0..31 of wave 0 ---
    if (t < K_) {
        float s = (vm_v == 0.f) ? -1e9f
                                : sc[t] * 0.0625f + logf(ew_v + 1e-6f) + lw_v;
        float mx = s;
        mx = fmaxf(mx, __shfl_xor(mx, 16)); mx = fmaxf(mx, __shfl_xor(mx, 8));
        mx = fmaxf(mx, __shfl_xor(mx, 4));  mx = fmaxf(mx, __shfl_xor(mx, 2));
        mx = fmaxf(mx, __shfl_xor(mx, 1));
        float ee = expf(s - mx);
        float ds = ee;
        ds += __shfl_xor(ds, 16); ds += __shfl_xor(ds, 8); ds += __shfl_xor(ds, 4);
        ds += __shfl_xor(ds, 2);  ds += __shfl_xor(ds, 1);
        at[t] = (ee / ds) * vw_m;       // fold vw[m]
    }
    __syncthreads();

    // --- both weighted sums from registers, dual LDS reduce buffers ---
    f32x4 pA = {0.f, 0.f, 0.f, 0.f};
    f32x4 pB = {0.f, 0.f, 0.f, 0.f};
#pragma unroll
    for (int i = 0; i < 8; ++i) {
        float a = at[i * 4 + w];        // h rows: k = 4i + w
        pA.x = fmaf(a, h4[i].x, pA.x);
        pA.y = fmaf(a, h4[i].y, pA.y);
        pA.z = fmaf(a, h4[i].z, pA.z);
        pA.w = fmaf(a, h4[i].w, pA.w);
        float g = at[w * 8 + i];        // lbl rows: k = 8w + i
        pB.x = fmaf(g, ld4[i].x, pB.x);
        pB.y = fmaf(g, ld4[i].y, pB.y);
        pB.z = fmaf(g, ld4[i].z, pB.z);
        pB.w = fmaf(g, ld4[i].w, pB.w);
    }
    *(f32x4*)&partA[w * D_ + 4 * l] = pA;
    *(f32x4*)&partB[w * D_ + 4 * l] = pB;
    __syncthreads();

    float hv = partA[t] + partA[D_ + t] + partA[2 * D_ + t] + partA[3 * D_ + t];
    hbar[(size_t)b * (M_ * D_) + m * D_ + t] = hv;
    float lv = partB[t] + partB[D_ + t] + partB[2 * D_ + t] + partB[3 * D_ + t];
    lblp[((size_t)m * B_ + b) * D_ + t] = lv;
}

// ---------------------------------------------------------------------------
// K3: out[b][e] = sum_kk hbar[b][kk]*W_Vflat[kk][e] + sum_m lblp[m][b][e]
// 16x64 tiles, grid (128,4)=512 blocks (2/CU) for latency hiding.
// ---------------------------------------------------------------------------
__global__ void __launch_bounds__(256) k3_gemm(const float* __restrict__ hbar,
                                               const float* __restrict__ W_V,
                                               const float* __restrict__ lblp,
                                               float* __restrict__ out) {
    int b0 = blockIdx.x * 16, e0 = blockIdx.y * 64;
    int t = threadIdx.x, tx = t & 15, ty = t >> 4;
    __shared__ float As[16 * PAD];
    __shared__ float Bs[64 * PAD];
    float c0 = 0.f, c1 = 0.f, c2 = 0.f, c3 = 0.f;
    for (int kc = 0; kc < M_ * D_; kc += 64) {
        {
            int bi = t >> 4, k4 = (t & 15) * 4;
            *(float4*)&As[bi * PAD + k4] =
                *(const float4*)&hbar[(size_t)(b0 + bi) * (M_ * D_) + kc + k4];
        }
#pragma unroll
        for (int it = 0; it < 4; ++it) {
            int s = it * 256 + t, kk = s >> 4, e4 = (s & 15) * 4;
            *(float4*)&Bs[kk * PAD + e4] =
                *(const float4*)&W_V[(size_t)(kc + kk) * D_ + e0 + e4];
        }
        __syncthreads();
#pragma unroll 4
        for (int kk = 0; kk < 64; ++kk) {
            float a0 = As[ty * PAD + kk];
            float4 b4 = *(const float4*)&Bs[kk * PAD + tx * 4];
            c0 = fmaf(a0, b4.x, c0);
            c1 = fmaf(a0, b4.y, c1);
            c2 = fmaf(a0, b4.z, c2);
            c3 = fmaf(a0, b4.w, c3);
        }
        __syncthreads();
    }
    int row = b0 + ty, col = e0 + tx * 4;
    float4 s = make_float4(c0, c1, c2, c3);
#pragma unroll
    for (int mm = 0; mm < 4; ++mm) {
        float4 lp = *(const float4*)&lblp[((size_t)mm * B_ + row) * D_ + col];
        s.x += lp.x; s.y += lp.y; s.z += lp.z; s.w += lp.w;
    }
    *(float4*)&out[(size_t)row * D_ + col] = s;
}

// ---------------------------------------------------------------------------
extern "C" void kernel_launch(void* const* d_in, const int* in_sizes, int n_in,
                              void* d_out, int out_size, void* d_ws, size_t ws_size,
                              hipStream_t stream) {
    const float* h_nei     = (const float*)d_in[0];
    const float* ew_anc    = (const float*)d_in[1];
    const float* vmask     = (const float*)d_in[2];
    const float* z_anc     = (const float*)d_in[3];
    const float* lbl_delta = (const float*)d_in[4];
    const float* lbl_w     = (const float*)d_in[5];
    const float* W_Q       = (const float*)d_in[6];
    const float* W_K       = (const float*)d_in[7];
    const float* W_V       = (const float*)d_in[8];
    const float* log_vw    = (const float*)d_in[9];
    float* out = (float*)d_out;

    // ws layout (floats):
    //   Wqk[4*128*256] | Qk[4*2048*256] | hbar[2048*1024] | lblp[4*2048*256]
    float* ws   = (float*)d_ws;
    float* Wqk  = ws;
    float* Qk   = Wqk + (M_ * DZ_ * D_);
    float* hbar = Qk + (M_ * B_ * D_);
    float* lblp = hbar + (B_ * M_ * D_);

    k0_wqk<<<M_ * DZ_, 256, 0, stream>>>(W_Q, W_K, Wqk);

    dim3 g1(B_ / 64, D_ / 64, M_);
    k1_qk<<<g1, 256, 0, stream>>>(z_anc, Wqk, Qk);

    k2_main<<<B_ * M_, 256, 0, stream>>>(h_nei, ew_anc, vmask, lbl_delta,
                                         lbl_w, Qk, log_vw, hbar, lblp);

    dim3 g3(B_ / 16, D_ / 64);
    k3_gemm<<<g3, 256, 0, stream>>>(hbar, W_V, lblp, out);
}